// Round 20
// baseline (114.665 us; speedup 1.0000x reference)
//
#include <hip/hip_runtime.h>
#include <hip/hip_bf16.h>
#include <cstdint>

#define B_ 2
#define S_ 4096
#define E_ 768
#define H_ 12
#define D_ 64
#define L2E 1.44269504088896f

typedef __bf16 bf16x8 __attribute__((ext_vector_type(8)));
typedef __bf16 bf16x4 __attribute__((ext_vector_type(4)));
typedef float f32x4 __attribute__((ext_vector_type(4)));
typedef float f32x16 __attribute__((ext_vector_type(16)));
typedef unsigned short ushort8 __attribute__((ext_vector_type(8)));
typedef unsigned short ushort4v __attribute__((ext_vector_type(4)));

static __device__ __forceinline__ unsigned short f2bf(float f) {
    union { float f; uint32_t u; } v; v.f = f;
    uint32_t u = v.u;
    u += 0x7FFFu + ((u >> 16) & 1u);
    return (unsigned short)(u >> 16);
}

static __device__ __forceinline__ void gl_lds16(const unsigned short* g, unsigned short* l) {
    __builtin_amdgcn_global_load_lds((const __attribute__((address_space(1))) unsigned int*)g,
                                     (__attribute__((address_space(3))) unsigned int*)l, 16, 0, 0);
}

static __device__ __forceinline__ f32x16 mfma32(bf16x8 a, bf16x8 b, f32x16 c) {
    return __builtin_amdgcn_mfma_f32_32x32x16_bf16(a, b, c, 0, 0, 0);
}

// ---------------- convert hidden_states fp32 -> bf16 ----------------
__global__ void cvt_x(const float* __restrict__ x, unsigned short* __restrict__ xb, int n4) {
    int i = blockIdx.x * blockDim.x + threadIdx.x;
    int stride = gridDim.x * blockDim.x;
    for (; i < n4; i += stride) {
        float4 f = ((const float4*)x)[i];
        ushort4v o;
        o.x = f2bf(f.x); o.y = f2bf(f.y); o.z = f2bf(f.z); o.w = f2bf(f.w);
        ((ushort4v*)xb)[i] = o;
    }
}

// ---------------- convert + transpose weights: WT[n][k] = W[k][n], bf16 ----------------
__global__ void cvt_w(const float* __restrict__ Wq, const float* __restrict__ Wk,
                      const float* __restrict__ Wv, unsigned short* __restrict__ wt) {
    __shared__ float tl[32][33];
    int wsel = blockIdx.z;
    const float* src = wsel == 0 ? Wq : (wsel == 1 ? Wk : Wv);
    int tx = threadIdx.x, ty = threadIdx.y;
    int n0 = blockIdx.x * 32, k0 = blockIdx.y * 32;
    for (int i = 0; i < 4; i++) {
        int k = k0 + ty + i * 8;
        tl[ty + i * 8][tx] = src[(size_t)k * E_ + n0 + tx];
    }
    __syncthreads();
    unsigned short* dst = wt + (size_t)wsel * E_ * E_;
    for (int i = 0; i < 4; i++) {
        int n = n0 + ty + i * 8;
        dst[(size_t)n * E_ + k0 + tx] = f2bf(tl[tx][ty + i * 8]);
    }
}

// ---------------- QKV GEMM: 128x128x32 2-phase double-buffered, gl_lds staging ----------------
// Q (pre-scaled by 0.125*log2e), K row-major bf16; V stored TRANSPOSED [b][h][d][s]
__global__ __launch_bounds__(256, 4) void qkv_gemm(const unsigned short* __restrict__ xb,
        const unsigned short* __restrict__ wt,
        const float* __restrict__ biasq, const float* __restrict__ biask,
        const float* __restrict__ biasv,
        unsigned short* __restrict__ qk, unsigned short* __restrict__ vtg) {
    __shared__ unsigned short lds[17920];      // A bufs @0,4096; B bufs @8192,12288; reused for epilogues
    unsigned short* ldsA = lds;
    unsigned short* ldsB = lds + 8192;

    // mtile-major XCD mapping: XCD x owns mtiles [x*8, x*8+8) x all 18 ntiles
    int bid = blockIdx.x;
    int mtile = (bid & 7) * 8 + ((bid >> 3) & 7);
    int ntile = bid >> 6;                      // 0..17
    int m0 = mtile * 128;
    int wsel = ntile / 6;
    int nb0 = ntile * 128 - wsel * E_;         // col offset within this weight
    const float* bias = wsel == 0 ? biasq : (wsel == 1 ? biask : biasv);
    float scale = wsel == 0 ? 0.125f * L2E : 1.0f;   // Q carries log2e for exp2 softmax

    int t = threadIdx.x, lane = t & 63, w = t >> 6;
    int l15 = lane & 15, l4 = lane >> 4;
    int wm = w >> 1, wn = w & 1;

    int rs = w * 16 + (lane >> 2);
    int cg = ((lane & 3) ^ ((rs >> 1) & 3)) * 8;
    const unsigned short* agp = xb + (size_t)(m0 + rs) * E_ + cg;
    const unsigned short* bgp = wt + (size_t)(wsel * E_ + nb0 + rs) * E_ + cg;

    f32x4 acc[4][4];
    #pragma unroll
    for (int f = 0; f < 4; f++)
        #pragma unroll
        for (int g = 0; g < 4; g++)
            acc[f][g] = (f32x4){0.f, 0.f, 0.f, 0.f};

    auto stage = [&](int kk, int buf) {
        gl_lds16(agp + kk,             ldsA + buf * 4096 + w * 512);
        gl_lds16(agp + kk + 64 * E_,   ldsA + buf * 4096 + 2048 + w * 512);
        gl_lds16(bgp + kk,             ldsB + buf * 4096 + w * 512);
        gl_lds16(bgp + kk + 64 * E_,   ldsB + buf * 4096 + 2048 + w * 512);
    };

    stage(0, 0);
    __syncthreads();

    int sA = (l4 ^ ((l15 >> 1) & 3)) * 8;      // swizzled k-slot for frag reads

    #pragma unroll 1
    for (int kt = 0; kt < 24; ++kt) {
        int buf = kt & 1;
        if (kt < 23) stage((kt + 1) * 32, buf ^ 1);
        bf16x8 b[4];
        #pragma unroll
        for (int g = 0; g < 4; g++)
            b[g] = *(const bf16x8*)&ldsB[buf * 4096 + (wn * 64 + g * 16 + l15) * 32 + sA];
        #pragma unroll
        for (int f = 0; f < 4; f++) {
            bf16x8 af = *(const bf16x8*)&ldsA[buf * 4096 + (wm * 64 + f * 16 + l15) * 32 + sA];
            #pragma unroll
            for (int g = 0; g < 4; g++)
                acc[f][g] = __builtin_amdgcn_mfma_f32_16x16x32_bf16(af, b[g], acc[f][g], 0, 0, 0);
        }
        __syncthreads();
    }

    if (wsel < 2) {
        // Q/K epilogue: LDS transpose, coalesced ushort8 stores
        const int QST = 140;
        #pragma unroll
        for (int f = 0; f < 4; f++) {
            #pragma unroll
            for (int g = 0; g < 4; g++) {
                int col = wn * 64 + g * 16 + l15;
                float bb = bias[nb0 + col];
                #pragma unroll
                for (int r = 0; r < 4; r++) {
                    int row = wm * 64 + f * 16 + l4 * 4 + r;
                    lds[row * QST + col] = f2bf((acc[f][g][r] + bb) * scale);
                }
            }
        }
        __syncthreads();
        int rr = t >> 4, l16 = t & 15;
        unsigned short* qbase = qk + (size_t)wsel * 8192 * E_;
        #pragma unroll
        for (int pas = 0; pas < 8; ++pas) {
            int row = pas * 16 + rr;
            ushort4v lo = *(const ushort4v*)&lds[row * QST + l16 * 8];
            ushort4v hi = *(const ushort4v*)&lds[row * QST + l16 * 8 + 4];
            ushort8 v8 = {lo.x, lo.y, lo.z, lo.w, hi.x, hi.y, hi.z, hi.w};
            *(ushort8*)(qbase + (size_t)(m0 + row) * E_ + nb0 + l16 * 8) = v8;
        }
    } else {
        // V epilogue: LDS transpose (p loop fully unrolled -> rule #20)
        const int TST = 134;
        int b2 = m0 >> 12;
        int s0 = m0 & 4095;
        #pragma unroll
        for (int p = 0; p < 2; ++p) {
            __syncthreads();
            #pragma unroll
            for (int gb = 0; gb < 2; ++gb) {
                int g = 2 * p + gb;
                int rid = wn * 32 + gb * 16 + l15;
                float bb = bias[nb0 + wn * 64 + g * 16 + l15];
                #pragma unroll
                for (int f = 0; f < 4; ++f) {
                    int sbase = wm * 64 + f * 16 + l4 * 4;
                    #pragma unroll
                    for (int r = 0; r < 4; ++r)
                        lds[rid * TST + sbase + r] = f2bf(acc[f][g][r] + bb);
                }
            }
            __syncthreads();
            int rid = t >> 2;
            int sc_ = (t & 3) * 32;
            int dcol = (rid >> 5) * 64 + (p * 2 + ((rid >> 4) & 1)) * 16 + (rid & 15);
            int gcol = nb0 + dcol;
            int hh = gcol >> 6, dd = gcol & 63;
            unsigned short* dst = vtg + ((size_t)(b2 * H_ + hh) * D_ + dd) * S_ + s0 + sc_;
            const unsigned short* srcl = lds + rid * TST + sc_;
            *(ushort8*)(dst)      = *(const ushort8*)(srcl);
            *(ushort8*)(dst + 8)  = *(const ushort8*)(srcl + 8);
            *(ushort8*)(dst + 16) = *(const ushort8*)(srcl + 16);
            *(ushort8*)(dst + 24) = *(const ushort8*)(srcl + 24);
        }
    }
}

// ---------------- banded flash attention: 32x32 MFMA, KVBLK=64 (grid-capped occupancy) ----------------
// 10 iterations of 64 keys (2 x 32-key subtiles). One barrier + one P-fence per 64 keys.
// LDS 52.5KB x 3 blocks/CU = 157.5KB fits; occupancy is grid-capped at 3 blocks/CU regardless.
__global__ __launch_bounds__(256) void attn(const unsigned short* __restrict__ qk,
        const unsigned short* __restrict__ vtg,
        const float* __restrict__ amask, float* __restrict__ out) {
    __shared__ unsigned short klds[2][4096];   // [buf][sub*2048 + key*64 + swz chunk]
    __shared__ unsigned short vlds[2][4096];   // [buf][sub*2048 + d*32 + swz slot]
    __shared__ unsigned short plds[4][2][1152];// per-wave P per subtile [32 q][32 k], stride 36
    __shared__ float fmlds[704];               // per-key additive mask (log2 units)

    // XCD-pinning: 96 blocks (3 bh-panels) per XCD
    int bid = blockIdx.x;
    int xcd = bid & 7;
    int j = bid >> 3;           // 0..95
    int qt = j & 31;            // 32 q-tiles of 128
    int p_ = xcd + 8 * (j >> 5);
    int h = p_ % H_;
    int b = p_ / H_;

    int t = threadIdx.x, lane = t & 63, wv = t >> 6;
    int l31 = lane & 31, lh = lane >> 5;
    const unsigned short* qp = qk;
    const unsigned short* kp = qk + (size_t)8192 * E_;
    size_t rowbase = (size_t)b * S_;
    int hcol = h * D_;
    const unsigned short* vth = vtg + (size_t)(b * H_ + h) * D_ * S_;
    const float* amb = amask + (size_t)b * S_;

    int qb0 = qt * 128;
    int q0w = qb0 + wv * 32;
    int myq = q0w + l31;

    // Q B-frags (col=q=l31, k=d)
    bf16x8 qbf[4];
    {
        const unsigned short* qrow = qp + (rowbase + myq) * E_ + hcol + lh * 8;
        qbf[0] = *(const bf16x8*)(qrow);
        qbf[1] = *(const bf16x8*)(qrow + 16);
        qbf[2] = *(const bf16x8*)(qrow + 32);
        qbf[3] = *(const bf16x8*)(qrow + 48);
    }

    int kt0 = qb0 - 256;

    // staging decode (verified swizzles; subtile s at +2048)
    int rK = t >> 3;                                   // K row 0..31
    int cK = (((t & 7) ^ (rK & 7)) << 3);
    const unsigned short* kbase_g = kp + rowbase * E_ + hcol + cK;
    int dV = t >> 2;                                   // V^T d-row 0..63
    int kcV = ((t & 3) ^ ((dV >> 1) & 3)) << 3;
    const unsigned short* vbase_g = vth + (size_t)dV * S_;

    auto stage = [&](int bt, int buf) {
        int kg = kt0 + bt * 64;
        int k0c = min(max(kg + rK, 0), S_ - 1);
        int k1c = min(max(kg + 32 + rK, 0), S_ - 1);
        gl_lds16(kbase_g + (size_t)k0c * E_, &klds[buf][wv * 512]);
        gl_lds16(kbase_g + (size_t)k1c * E_, &klds[buf][2048 + wv * 512]);
        int v0 = min(max(kg + kcV, 0), S_ - 8);
        int v1 = min(max(kg + 32 + kcV, 0), S_ - 8);
        gl_lds16(vbase_g + v0, &vlds[buf][wv * 512]);
        gl_lds16(vbase_g + v1, &vlds[buf][2048 + wv * 512]);
    };

    stage(0, 0);

    // per-key additive mask + block-uniform nonzero flag
    int nz = 0;
    for (int i = t; i < 704; i += 256) {
        int key = kt0 + i;
        float v = 0.f;
        if (i < 640 && key >= 0 && key < S_) {
            float a = amb[key];
            if (a != 0.f) { v = -10000.f * L2E; nz = 1; }
        }
        fmlds[i] = v;
    }
    bool usefm = __syncthreads_or(nz) != 0;

    const float C_ = 12.0f;
    float lpart = 0.f;
    f32x16 oacc0 = {0.f,0.f,0.f,0.f,0.f,0.f,0.f,0.f,0.f,0.f,0.f,0.f,0.f,0.f,0.f,0.f};
    f32x16 oacc1 = {0.f,0.f,0.f,0.f,0.f,0.f,0.f,0.f,0.f,0.f,0.f,0.f,0.f,0.f,0.f,0.f};
    unsigned short* pl0 = (unsigned short*)plds[wv][0];
    unsigned short* pl1 = (unsigned short*)plds[wv][1];

    // read addresses (elems)
    int kaddr0 = l31 * 64 + (((0 + lh) ^ (l31 & 7)) << 3);
    int kaddr1 = l31 * 64 + (((2 + lh) ^ (l31 & 7)) << 3);
    int kaddr2 = l31 * 64 + (((4 + lh) ^ (l31 & 7)) << 3);
    int kaddr3 = l31 * 64 + (((6 + lh) ^ (l31 & 7)) << 3);
    int vaddr0 = l31 * 32 + (((lh + 0) ^ ((l31 >> 1) & 3)) << 3);
    int vaddr1 = l31 * 32 + (((lh + 2) ^ ((l31 >> 1) & 3)) << 3);
    int pw = l31 * 36 + 4 * lh;
    int pr = l31 * 36 + 8 * lh;

    #pragma unroll 1
    for (int bt = 0; bt < 10; ++bt) {
        int buf = bt & 1;
        __syncthreads();                       // stage(bt) landed; buf^1 free
        if (bt + 1 < 10) stage(bt + 1, buf ^ 1);
        int kg = kt0 + bt * 64;

        // --- V^T A-frags, both subtiles (issue early; consumed after fence)
        bf16x8 va000 = *(const bf16x8*)&vlds[buf][vaddr0];
        bf16x8 va001 = *(const bf16x8*)&vlds[buf][vaddr1];
        bf16x8 va010 = *(const bf16x8*)&vlds[buf][1024 + vaddr0];
        bf16x8 va011 = *(const bf16x8*)&vlds[buf][1024 + vaddr1];
        bf16x8 va100 = *(const bf16x8*)&vlds[buf][2048 + vaddr0];
        bf16x8 va101 = *(const bf16x8*)&vlds[buf][2048 + vaddr1];
        bf16x8 va110 = *(const bf16x8*)&vlds[buf][3072 + vaddr0];
        bf16x8 va111 = *(const bf16x8*)&vlds[buf][3072 + vaddr1];

        // ===== subtile 0: QK^T + softmax + P write =====
        {
            bf16x8 ka0 = *(const bf16x8*)&klds[buf][kaddr0];
            bf16x8 ka1 = *(const bf16x8*)&klds[buf][kaddr1];
            bf16x8 ka2 = *(const bf16x8*)&klds[buf][kaddr2];
            bf16x8 ka3 = *(const bf16x8*)&klds[buf][kaddr3];
            f32x16 st = {0.f,0.f,0.f,0.f,0.f,0.f,0.f,0.f,0.f,0.f,0.f,0.f,0.f,0.f,0.f,0.f};
            st = mfma32(ka0, qbf[0], st);
            st = mfma32(ka1, qbf[1], st);
            st = mfma32(ka2, qbf[2], st);
            st = mfma32(ka3, qbf[3], st);
            bool fullt = (kg >= q0w + 31 - 256) && (kg + 31 <= q0w + 256) &&
                         (kg >= 0) && (kg + 31 < S_);
            float sv[16];
            if (fullt) {
                if (usefm) {
                    int fo = bt * 64 + 4 * lh;
                    float4 f0 = *(const float4*)&fmlds[fo];
                    float4 f1 = *(const float4*)&fmlds[fo + 8];
                    float4 f2 = *(const float4*)&fmlds[fo + 16];
                    float4 f3 = *(const float4*)&fmlds[fo + 24];
                    sv[0]=st[0]+f0.x;  sv[1]=st[1]+f0.y;  sv[2]=st[2]+f0.z;  sv[3]=st[3]+f0.w;
                    sv[4]=st[4]+f1.x;  sv[5]=st[5]+f1.y;  sv[6]=st[6]+f1.z;  sv[7]=st[7]+f1.w;
                    sv[8]=st[8]+f2.x;  sv[9]=st[9]+f2.y;  sv[10]=st[10]+f2.z; sv[11]=st[11]+f2.w;
                    sv[12]=st[12]+f3.x; sv[13]=st[13]+f3.y; sv[14]=st[14]+f3.z; sv[15]=st[15]+f3.w;
                } else {
                    #pragma unroll
                    for (int i = 0; i < 16; i++) sv[i] = st[i];
                }
            } else {
                int lo = max(myq - 256, 0) - kg;
                int hi = min(myq + 256, S_ - 1) - kg;
                #pragma unroll
                for (int i = 0; i < 16; i++) {
                    int idx = (i & 3) + 8 * (i >> 2) + 4 * lh;
                    float s = st[i];
                    if (usefm) s += fmlds[bt * 64 + idx];
                    sv[i] = (idx >= lo && idx <= hi) ? s : -1e30f;
                }
            }
            bf16x4 pb[4];
            float ps = 0.f;
            #pragma unroll
            for (int g = 0; g < 4; g++) {
                #pragma unroll
                for (int rr = 0; rr < 4; rr++) {
                    float e = exp2f(sv[4 * g + rr] - C_);
                    ps += e;
                    pb[g][rr] = (__bf16)e;
                }
            }
            lpart += ps;
            #pragma unroll
            for (int g = 0; g < 4; g++)
                *(ushort4v*)(pl0 + pw + 8 * g) = __builtin_bit_cast(ushort4v, pb[g]);
        }

        // ===== subtile 1: QK^T + softmax + P write =====
        {
            int kg1 = kg + 32;
            bf16x8 ka0 = *(const bf16x8*)&klds[buf][2048 + kaddr0];
            bf16x8 ka1 = *(const bf16x8*)&klds[buf][2048 + kaddr1];
            bf16x8 ka2 = *(const bf16x8*)&klds[buf][2048 + kaddr2];
            bf16x8 ka3 = *(const bf16x8*)&klds[buf][2048 + kaddr3];
            f32x16 st = {0.f,0.f,0.f,0.f,0.f,0.f,0.f,0.f,0.f,0.f,0.f,0.f,0.f,0.f,0.f,0.f};
            st = mfma32(ka0, qbf[0], st);
            st = mfma32(ka1, qbf[1], st);
            st = mfma32(ka2, qbf[2], st);
            st = mfma32(ka3, qbf[3], st);
            bool fullt = (kg1 >= q0w + 31 - 256) && (kg1 + 31 <= q0w + 256) &&
                         (kg1 >= 0) && (kg1 + 31 < S_);
            float sv[16];
            if (fullt) {
                if (usefm) {
                    int fo = bt * 64 + 32 + 4 * lh;
                    float4 f0 = *(const float4*)&fmlds[fo];
                    float4 f1 = *(const float4*)&fmlds[fo + 8];
                    float4 f2 = *(const float4*)&fmlds[fo + 16];
                    float4 f3 = *(const float4*)&fmlds[fo + 24];
                    sv[0]=st[0]+f0.x;  sv[1]=st[1]+f0.y;  sv[2]=st[2]+f0.z;  sv[3]=st[3]+f0.w;
                    sv[4]=st[4]+f1.x;  sv[5]=st[5]+f1.y;  sv[6]=st[6]+f1.z;  sv[7]=st[7]+f1.w;
                    sv[8]=st[8]+f2.x;  sv[9]=st[9]+f2.y;  sv[10]=st[10]+f2.z; sv[11]=st[11]+f2.w;
                    sv[12]=st[12]+f3.x; sv[13]=st[13]+f3.y; sv[14]=st[14]+f3.z; sv[15]=st[15]+f3.w;
                } else {
                    #pragma unroll
                    for (int i = 0; i < 16; i++) sv[i] = st[i];
                }
            } else {
                int lo = max(myq - 256, 0) - kg1;
                int hi = min(myq + 256, S_ - 1) - kg1;
                #pragma unroll
                for (int i = 0; i < 16; i++) {
                    int idx = (i & 3) + 8 * (i >> 2) + 4 * lh;
                    float s = st[i];
                    if (usefm) s += fmlds[bt * 64 + 32 + idx];
                    sv[i] = (idx >= lo && idx <= hi) ? s : -1e30f;
                }
            }
            bf16x4 pb[4];
            float ps = 0.f;
            #pragma unroll
            for (int g = 0; g < 4; g++) {
                #pragma unroll
                for (int rr = 0; rr < 4; rr++) {
                    float e = exp2f(sv[4 * g + rr] - C_);
                    ps += e;
                    pb[g][rr] = (__bf16)e;
                }
            }
            lpart += ps;
            #pragma unroll
            for (int g = 0; g < 4; g++)
                *(ushort4v*)(pl1 + pw + 8 * g) = __builtin_bit_cast(ushort4v, pb[g]);
        }

        // --- one fence for both subtiles' P
        asm volatile("s_waitcnt lgkmcnt(0)" ::: "memory");
        __builtin_amdgcn_sched_barrier(0);
        bf16x8 pf00 = *(const bf16x8*)(pl0 + pr);
        bf16x8 pf01 = *(const bf16x8*)(pl0 + pr + 16);
        bf16x8 pf10 = *(const bf16x8*)(pl1 + pr);
        bf16x8 pf11 = *(const bf16x8*)(pl1 + pr + 16);

        // --- PV: O^T[d][q] += V^T x P^T, both subtiles
        oacc0 = mfma32(va000, pf00, oacc0);
        oacc0 = mfma32(va001, pf01, oacc0);
        oacc1 = mfma32(va010, pf00, oacc1);
        oacc1 = mfma32(va011, pf01, oacc1);
        oacc0 = mfma32(va100, pf10, oacc0);
        oacc0 = mfma32(va101, pf11, oacc0);
        oacc1 = mfma32(va110, pf10, oacc1);
        oacc1 = mfma32(va111, pf11, oacc1);
    }

    // --- epilogue: lane holds col q=myq, rows d = (r&3)+8*(r>>2)+4lh (+32)
    float lsum = lpart + __shfl_xor(lpart, 32);
    float inv = 1.0f / lsum;
    if (amb[myq] < 0.f) inv = 0.f;
    float* orow = out + (rowbase + myq) * E_ + hcol;
    #pragma unroll
    for (int g = 0; g < 4; g++) {
        float4 o0, o1;
        o0.x = oacc0[4 * g + 0] * inv; o0.y = oacc0[4 * g + 1] * inv;
        o0.z = oacc0[4 * g + 2] * inv; o0.w = oacc0[4 * g + 3] * inv;
        o1.x = oacc1[4 * g + 0] * inv; o1.y = oacc1[4 * g + 1] * inv;
        o1.z = oacc1[4 * g + 2] * inv; o1.w = oacc1[4 * g + 3] * inv;
        *(float4*)(orow + 8 * g + 4 * lh)      = o0;
        *(float4*)(orow + 32 + 8 * g + 4 * lh) = o1;
    }
}

extern "C" void kernel_launch(void* const* d_in, const int* in_sizes, int n_in,
                              void* d_out, int out_size, void* d_ws, size_t ws_size,
                              hipStream_t stream) {
    const float* hs = (const float*)d_in[0];
    const float* am = (const float*)d_in[1];
    const float* Wq = (const float*)d_in[2];
    const float* bq = (const float*)d_in[3];
    const float* Wk = (const float*)d_in[4];
    const float* bk = (const float*)d_in[5];
    const float* Wv = (const float*)d_in[6];
    const float* bv = (const float*)d_in[7];
    float* out = (float*)d_out;
    unsigned short* xb  = (unsigned short*)d_ws;                  // 8192*768
    unsigned short* wtp = xb + (size_t)8192 * E_;                 // 3*768*768
    unsigned short* qkb = wtp + (size_t)3 * E_ * E_;              // 2*8192*768 (Q,K)
    unsigned short* vtg = qkb + (size_t)2 * 8192 * E_;            // 2*12*64*4096 (V^T)

    hipLaunchKernelGGL(cvt_x, dim3(2048), dim3(256), 0, stream, hs, xb, 8192 * E_ / 4);
    hipLaunchKernelGGL(cvt_w, dim3(24, 24, 3), dim3(32, 8), 0, stream, Wq, Wk, Wv, wtp);
    hipLaunchKernelGGL(qkv_gemm, dim3(1152), dim3(256), 0, stream, xb, wtp, bq, bk, bv, qkb, vtg);
    hipLaunchKernelGGL(attn, dim3(768), dim3(256), 0, stream, qkb, vtg, am, out);
}

// Round 21
// 101.101 us; speedup vs baseline: 1.1342x; 1.1342x over previous
//
#include <hip/hip_runtime.h>
#include <hip/hip_bf16.h>
#include <cstdint>

#define B_ 2
#define S_ 4096
#define E_ 768
#define H_ 12
#define D_ 64
#define L2E 1.44269504088896f

typedef __bf16 bf16x8 __attribute__((ext_vector_type(8)));
typedef __bf16 bf16x4 __attribute__((ext_vector_type(4)));
typedef float f32x4 __attribute__((ext_vector_type(4)));
typedef float f32x16 __attribute__((ext_vector_type(16)));
typedef unsigned short ushort8 __attribute__((ext_vector_type(8)));
typedef unsigned short ushort4v __attribute__((ext_vector_type(4)));

static __device__ __forceinline__ unsigned short f2bf(float f) {
    union { float f; uint32_t u; } v; v.f = f;
    uint32_t u = v.u;
    u += 0x7FFFu + ((u >> 16) & 1u);
    return (unsigned short)(u >> 16);
}

static __device__ __forceinline__ void gl_lds16(const unsigned short* g, unsigned short* l) {
    __builtin_amdgcn_global_load_lds((const __attribute__((address_space(1))) unsigned int*)g,
                                     (__attribute__((address_space(3))) unsigned int*)l, 16, 0, 0);
}

static __device__ __forceinline__ f32x16 mfma32(bf16x8 a, bf16x8 b, f32x16 c) {
    return __builtin_amdgcn_mfma_f32_32x32x16_bf16(a, b, c, 0, 0, 0);
}

// ---------------- fused convert: hidden_states fp32->bf16 AND W^T bf16 ----------------
// blocks [0,2048): grid-stride float4 conversion of X
// blocks [2048,3776): 32x32 transpose tiles of Wq/Wk/Wv
__global__ void cvt_fused(const float* __restrict__ x, unsigned short* __restrict__ xb, int n4,
                          const float* __restrict__ Wq, const float* __restrict__ Wk,
                          const float* __restrict__ Wv, unsigned short* __restrict__ wt) {
    __shared__ float tl[32][33];
    int bid = blockIdx.x;
    int t = threadIdx.x;
    if (bid < 2048) {
        int i = bid * 256 + t;
        int stride = 2048 * 256;
        for (; i < n4; i += stride) {
            float4 f = ((const float4*)x)[i];
            ushort4v o;
            o.x = f2bf(f.x); o.y = f2bf(f.y); o.z = f2bf(f.z); o.w = f2bf(f.w);
            ((ushort4v*)xb)[i] = o;
        }
    } else {
        int wb = bid - 2048;                  // 0..1727
        int wsel = wb / 576;
        int rem = wb % 576;
        int n0 = (rem % 24) * 32, k0 = (rem / 24) * 32;
        const float* src = wsel == 0 ? Wq : (wsel == 1 ? Wk : Wv);
        int tx = t & 31, ty = t >> 5;         // 32 x 8
        for (int i = 0; i < 4; i++) {
            int k = k0 + ty + i * 8;
            tl[ty + i * 8][tx] = src[(size_t)k * E_ + n0 + tx];
        }
        __syncthreads();
        unsigned short* dst = wt + (size_t)wsel * E_ * E_;
        for (int i = 0; i < 4; i++) {
            int n = n0 + ty + i * 8;
            dst[(size_t)n * E_ + k0 + tx] = f2bf(tl[tx][ty + i * 8]);
        }
    }
}

// ---------------- QKV GEMM: 128x128x32 2-phase double-buffered, gl_lds staging ----------------
// Q (pre-scaled by 0.125*log2e), K row-major bf16; V stored TRANSPOSED [b][h][d][s]
__global__ __launch_bounds__(256, 4) void qkv_gemm(const unsigned short* __restrict__ xb,
        const unsigned short* __restrict__ wt,
        const float* __restrict__ biasq, const float* __restrict__ biask,
        const float* __restrict__ biasv,
        unsigned short* __restrict__ qk, unsigned short* __restrict__ vtg) {
    __shared__ unsigned short lds[17920];      // A bufs @0,4096; B bufs @8192,12288; reused for epilogues
    unsigned short* ldsA = lds;
    unsigned short* ldsB = lds + 8192;

    // mtile-major XCD mapping: XCD x owns mtiles [x*8, x*8+8) x all 18 ntiles
    int bid = blockIdx.x;
    int mtile = (bid & 7) * 8 + ((bid >> 3) & 7);
    int ntile = bid >> 6;                      // 0..17
    int m0 = mtile * 128;
    int wsel = ntile / 6;
    int nb0 = ntile * 128 - wsel * E_;         // col offset within this weight
    const float* bias = wsel == 0 ? biasq : (wsel == 1 ? biask : biasv);
    float scale = wsel == 0 ? 0.125f * L2E : 1.0f;   // Q carries log2e for exp2 softmax

    int t = threadIdx.x, lane = t & 63, w = t >> 6;
    int l15 = lane & 15, l4 = lane >> 4;
    int wm = w >> 1, wn = w & 1;

    int rs = w * 16 + (lane >> 2);
    int cg = ((lane & 3) ^ ((rs >> 1) & 3)) * 8;
    const unsigned short* agp = xb + (size_t)(m0 + rs) * E_ + cg;
    const unsigned short* bgp = wt + (size_t)(wsel * E_ + nb0 + rs) * E_ + cg;

    f32x4 acc[4][4];
    #pragma unroll
    for (int f = 0; f < 4; f++)
        #pragma unroll
        for (int g = 0; g < 4; g++)
            acc[f][g] = (f32x4){0.f, 0.f, 0.f, 0.f};

    auto stage = [&](int kk, int buf) {
        gl_lds16(agp + kk,             ldsA + buf * 4096 + w * 512);
        gl_lds16(agp + kk + 64 * E_,   ldsA + buf * 4096 + 2048 + w * 512);
        gl_lds16(bgp + kk,             ldsB + buf * 4096 + w * 512);
        gl_lds16(bgp + kk + 64 * E_,   ldsB + buf * 4096 + 2048 + w * 512);
    };

    stage(0, 0);
    __syncthreads();

    int sA = (l4 ^ ((l15 >> 1) & 3)) * 8;      // swizzled k-slot for frag reads

    #pragma unroll 1
    for (int kt = 0; kt < 24; ++kt) {
        int buf = kt & 1;
        if (kt < 23) stage((kt + 1) * 32, buf ^ 1);
        bf16x8 b[4];
        #pragma unroll
        for (int g = 0; g < 4; g++)
            b[g] = *(const bf16x8*)&ldsB[buf * 4096 + (wn * 64 + g * 16 + l15) * 32 + sA];
        #pragma unroll
        for (int f = 0; f < 4; f++) {
            bf16x8 af = *(const bf16x8*)&ldsA[buf * 4096 + (wm * 64 + f * 16 + l15) * 32 + sA];
            #pragma unroll
            for (int g = 0; g < 4; g++)
                acc[f][g] = __builtin_amdgcn_mfma_f32_16x16x32_bf16(af, b[g], acc[f][g], 0, 0, 0);
        }
        __syncthreads();
    }

    if (wsel < 2) {
        // Q/K epilogue: LDS transpose, coalesced ushort8 stores
        const int QST = 140;
        #pragma unroll
        for (int f = 0; f < 4; f++) {
            #pragma unroll
            for (int g = 0; g < 4; g++) {
                int col = wn * 64 + g * 16 + l15;
                float bb = bias[nb0 + col];
                #pragma unroll
                for (int r = 0; r < 4; r++) {
                    int row = wm * 64 + f * 16 + l4 * 4 + r;
                    lds[row * QST + col] = f2bf((acc[f][g][r] + bb) * scale);
                }
            }
        }
        __syncthreads();
        int rr = t >> 4, l16 = t & 15;
        unsigned short* qbase = qk + (size_t)wsel * 8192 * E_;
        #pragma unroll
        for (int pas = 0; pas < 8; ++pas) {
            int row = pas * 16 + rr;
            ushort4v lo = *(const ushort4v*)&lds[row * QST + l16 * 8];
            ushort4v hi = *(const ushort4v*)&lds[row * QST + l16 * 8 + 4];
            ushort8 v8 = {lo.x, lo.y, lo.z, lo.w, hi.x, hi.y, hi.z, hi.w};
            *(ushort8*)(qbase + (size_t)(m0 + row) * E_ + nb0 + l16 * 8) = v8;
        }
    } else {
        // V epilogue: LDS transpose (p loop fully unrolled -> rule #20)
        const int TST = 134;
        int b2 = m0 >> 12;
        int s0 = m0 & 4095;
        #pragma unroll
        for (int p = 0; p < 2; ++p) {
            __syncthreads();
            #pragma unroll
            for (int gb = 0; gb < 2; ++gb) {
                int g = 2 * p + gb;
                int rid = wn * 32 + gb * 16 + l15;
                float bb = bias[nb0 + wn * 64 + g * 16 + l15];
                #pragma unroll
                for (int f = 0; f < 4; ++f) {
                    int sbase = wm * 64 + f * 16 + l4 * 4;
                    #pragma unroll
                    for (int r = 0; r < 4; ++r)
                        lds[rid * TST + sbase + r] = f2bf(acc[f][g][r] + bb);
                }
            }
            __syncthreads();
            int rid = t >> 2;
            int sc_ = (t & 3) * 32;
            int dcol = (rid >> 5) * 64 + (p * 2 + ((rid >> 4) & 1)) * 16 + (rid & 15);
            int gcol = nb0 + dcol;
            int hh = gcol >> 6, dd = gcol & 63;
            unsigned short* dst = vtg + ((size_t)(b2 * H_ + hh) * D_ + dd) * S_ + s0 + sc_;
            const unsigned short* srcl = lds + rid * TST + sc_;
            *(ushort8*)(dst)      = *(const ushort8*)(srcl);
            *(ushort8*)(dst + 8)  = *(const ushort8*)(srcl + 8);
            *(ushort8*)(dst + 16) = *(const ushort8*)(srcl + 16);
            *(ushort8*)(dst + 24) = *(const ushort8*)(srcl + 24);
        }
    }
}

// ---------------- banded flash attention: 32x32 MFMA, 32 q/wave, 128 q/block (r14 verbatim) ----------------
__global__ __launch_bounds__(256) void attn(const unsigned short* __restrict__ qk,
        const unsigned short* __restrict__ vtg,
        const float* __restrict__ amask, float* __restrict__ out) {
    __shared__ unsigned short klds[2][2048];   // [buf] K: 32 keys x 64 d, chunk-swizzled
    __shared__ unsigned short vlds[2][2048];   // [buf] V^T: 64 d x 32 keys, chunk-swizzled
    __shared__ unsigned short plds[4][32 * 36];// per-wave P [32 q][32 keys], stride 36
    __shared__ float fmlds[640];               // per-key additive mask (log2 units)

    // XCD-pinning: 96 blocks (3 bh-panels) per XCD
    int bid = blockIdx.x;
    int xcd = bid & 7;
    int j = bid >> 3;           // 0..95
    int qt = j & 31;            // 32 q-tiles of 128
    int p_ = xcd + 8 * (j >> 5);
    int h = p_ % H_;
    int b = p_ / H_;

    int t = threadIdx.x, lane = t & 63, wv = t >> 6;
    int l31 = lane & 31, lh = lane >> 5;
    const unsigned short* qp = qk;
    const unsigned short* kp = qk + (size_t)8192 * E_;
    size_t rowbase = (size_t)b * S_;
    int hcol = h * D_;
    const unsigned short* vth = vtg + (size_t)(b * H_ + h) * D_ * S_;
    const float* amb = amask + (size_t)b * S_;

    int qb0 = qt * 128;
    int q0w = qb0 + wv * 32;
    int myq = q0w + l31;

    // Q B-frags (col=q=l31, k=d=16s + lh*8 + j)
    bf16x8 qbf[4];
    {
        const unsigned short* qrow = qp + (rowbase + myq) * E_ + hcol + lh * 8;
        qbf[0] = *(const bf16x8*)(qrow);
        qbf[1] = *(const bf16x8*)(qrow + 16);
        qbf[2] = *(const bf16x8*)(qrow + 32);
        qbf[3] = *(const bf16x8*)(qrow + 48);
    }

    int kt0 = qb0 - 256;

    // staging decode (both-sides swizzle invariants preserved)
    int rK = t >> 3;                                   // K row 0..31
    int cK = (((t & 7) ^ (rK & 7)) << 3);
    const unsigned short* kbase_g = kp + rowbase * E_ + hcol + cK;
    int dV = t >> 2;                                   // V^T d-row 0..63
    int kcV = ((t & 3) ^ ((dV >> 1) & 3)) << 3;
    const unsigned short* vbase_g = vth + (size_t)dV * S_;

    auto stage = [&](int bt, int buf) {
        int kg = kt0 + bt * 32;
        int kk = min(max(kg + rK, 0), S_ - 1);
        gl_lds16(kbase_g + (size_t)kk * E_, &klds[buf][wv * 512]);
        int vb = min(max(kg + kcV, 0), S_ - 8);
        gl_lds16(vbase_g + vb, &vlds[buf][wv * 512]);
    };

    stage(0, 0);

    // per-key additive mask + block-uniform nonzero flag
    int nz = 0;
    for (int i = t; i < 640; i += 256) {
        int key = kt0 + i;
        float v = 0.f;
        if (key >= 0 && key < S_) {
            float a = amb[key];
            if (a != 0.f) { v = -10000.f * L2E; nz = 1; }
        }
        fmlds[i] = v;
    }
    bool usefm = __syncthreads_or(nz) != 0;

    const float C_ = 12.0f;
    float lpart = 0.f;
    f32x16 oacc0 = {0.f,0.f,0.f,0.f,0.f,0.f,0.f,0.f,0.f,0.f,0.f,0.f,0.f,0.f,0.f,0.f};
    f32x16 oacc1 = {0.f,0.f,0.f,0.f,0.f,0.f,0.f,0.f,0.f,0.f,0.f,0.f,0.f,0.f,0.f,0.f};
    unsigned short* pl = (unsigned short*)plds[wv];

    // read addresses (elems)
    int kaddr0 = l31 * 64 + (((0 + lh) ^ (l31 & 7)) << 3);     // g = 2s + lh
    int kaddr1 = l31 * 64 + (((2 + lh) ^ (l31 & 7)) << 3);
    int kaddr2 = l31 * 64 + (((4 + lh) ^ (l31 & 7)) << 3);
    int kaddr3 = l31 * 64 + (((6 + lh) ^ (l31 & 7)) << 3);
    int vaddr0 = l31 * 32 + (((lh + 0) ^ ((l31 >> 1) & 3)) << 3);  // f=0
    int vaddr1 = l31 * 32 + (((lh + 2) ^ ((l31 >> 1) & 3)) << 3);  // f=1
    int pw = l31 * 36 + 4 * lh;    // P write base (cols 8g + 4lh)
    int pr = l31 * 36 + 8 * lh;    // P read base (keys 8lh / 16+8lh)

    #pragma unroll 1
    for (int bt = 0; bt < 20; ++bt) {
        int buf = bt & 1;
        __syncthreads();                       // stage(bt) landed; buf^1 free
        if (bt + 1 < 20) stage(bt + 1, buf ^ 1);
        int kg = kt0 + bt * 32;

        // --- K A-frags (row=key=l31, k=d)
        bf16x8 ka0 = *(const bf16x8*)&klds[buf][kaddr0];
        bf16x8 ka1 = *(const bf16x8*)&klds[buf][kaddr1];
        bf16x8 ka2 = *(const bf16x8*)&klds[buf][kaddr2];
        bf16x8 ka3 = *(const bf16x8*)&klds[buf][kaddr3];

        // --- V^T A-frags (row=d, k=key), two d-tiles
        bf16x8 va00 = *(const bf16x8*)&vlds[buf][vaddr0];
        bf16x8 va01 = *(const bf16x8*)&vlds[buf][vaddr1];
        bf16x8 va10 = *(const bf16x8*)&vlds[buf][1024 + vaddr0];
        bf16x8 va11 = *(const bf16x8*)&vlds[buf][1024 + vaddr1];

        // --- swapped QK^T: S^T[key][q], K-accumulate over D=64
        f32x16 st = {0.f,0.f,0.f,0.f,0.f,0.f,0.f,0.f,0.f,0.f,0.f,0.f,0.f,0.f,0.f,0.f};
        st = mfma32(ka0, qbf[0], st);
        st = mfma32(ka1, qbf[1], st);
        st = mfma32(ka2, qbf[2], st);
        st = mfma32(ka3, qbf[3], st);

        // tile fully valid for this wave? (wave-uniform)
        bool fullt = (kg >= q0w + 31 - 256) && (kg + 31 <= q0w + 256) &&
                     (kg >= 0) && (kg + 31 < S_);
        float sv[16];
        if (fullt) {
            if (usefm) {
                int fo = bt * 32 + 4 * lh;
                float4 f0 = *(const float4*)&fmlds[fo];
                float4 f1 = *(const float4*)&fmlds[fo + 8];
                float4 f2 = *(const float4*)&fmlds[fo + 16];
                float4 f3 = *(const float4*)&fmlds[fo + 24];
                sv[0]=st[0]+f0.x;  sv[1]=st[1]+f0.y;  sv[2]=st[2]+f0.z;  sv[3]=st[3]+f0.w;
                sv[4]=st[4]+f1.x;  sv[5]=st[5]+f1.y;  sv[6]=st[6]+f1.z;  sv[7]=st[7]+f1.w;
                sv[8]=st[8]+f2.x;  sv[9]=st[9]+f2.y;  sv[10]=st[10]+f2.z; sv[11]=st[11]+f2.w;
                sv[12]=st[12]+f3.x; sv[13]=st[13]+f3.y; sv[14]=st[14]+f3.z; sv[15]=st[15]+f3.w;
            } else {
                #pragma unroll
                for (int i = 0; i < 16; i++) sv[i] = st[i];
            }
        } else {
            // band+range as one [lo,hi] interval on tile-local key idx
            int lo = max(myq - 256, 0) - kg;
            int hi = min(myq + 256, S_ - 1) - kg;
            #pragma unroll
            for (int i = 0; i < 16; i++) {
                int idx = (i & 3) + 8 * (i >> 2) + 4 * lh;   // key = kg + idx
                float s = st[i];
                if (usefm) s += fmlds[bt * 32 + idx];
                sv[i] = (idx >= lo && idx <= hi) ? s : -1e30f;
            }
        }

        // --- fixed-shift softmax (log2 domain): P = 2^(sv - C)
        bf16x4 pb[4];
        float ps = 0.f;
        #pragma unroll
        for (int g = 0; g < 4; g++) {
            #pragma unroll
            for (int rr = 0; rr < 4; rr++) {
                float e = exp2f(sv[4 * g + rr] - C_);
                ps += e;
                pb[g][rr] = (__bf16)e;
            }
        }
        lpart += ps;

        // --- P round-trip: LDS [q][key], keys (r&3)+8g+4lh contiguous per g
        #pragma unroll
        for (int g = 0; g < 4; g++)
            *(ushort4v*)(pl + pw + 8 * g) = __builtin_bit_cast(ushort4v, pb[g]);
        asm volatile("s_waitcnt lgkmcnt(0)" ::: "memory");
        __builtin_amdgcn_sched_barrier(0);
        bf16x8 pf0 = *(const bf16x8*)(pl + pr);        // k = 0..15
        bf16x8 pf1 = *(const bf16x8*)(pl + pr + 16);   // k = 16..31

        // --- PV: O^T[d][q] += V^T x P^T
        oacc0 = mfma32(va00, pf0, oacc0);
        oacc0 = mfma32(va01, pf1, oacc0);
        oacc1 = mfma32(va10, pf0, oacc1);
        oacc1 = mfma32(va11, pf1, oacc1);
    }

    // --- epilogue: lane holds col q=myq, rows d = (r&3)+8*(r>>2)+4lh (+32)
    float lsum = lpart + __shfl_xor(lpart, 32);
    float inv = 1.0f / lsum;
    if (amb[myq] < 0.f) inv = 0.f;
    float* orow = out + (rowbase + myq) * E_ + hcol;
    #pragma unroll
    for (int g = 0; g < 4; g++) {
        float4 o0, o1;
        o0.x = oacc0[4 * g + 0] * inv; o0.y = oacc0[4 * g + 1] * inv;
        o0.z = oacc0[4 * g + 2] * inv; o0.w = oacc0[4 * g + 3] * inv;
        o1.x = oacc1[4 * g + 0] * inv; o1.y = oacc1[4 * g + 1] * inv;
        o1.z = oacc1[4 * g + 2] * inv; o1.w = oacc1[4 * g + 3] * inv;
        *(float4*)(orow + 8 * g + 4 * lh)      = o0;
        *(float4*)(orow + 32 + 8 * g + 4 * lh) = o1;
    }
}

extern "C" void kernel_launch(void* const* d_in, const int* in_sizes, int n_in,
                              void* d_out, int out_size, void* d_ws, size_t ws_size,
                              hipStream_t stream) {
    const float* hs = (const float*)d_in[0];
    const float* am = (const float*)d_in[1];
    const float* Wq = (const float*)d_in[2];
    const float* bq = (const float*)d_in[3];
    const float* Wk = (const float*)d_in[4];
    const float* bk = (const float*)d_in[5];
    const float* Wv = (const float*)d_in[6];
    const float* bv = (const float*)d_in[7];
    float* out = (float*)d_out;
    unsigned short* xb  = (unsigned short*)d_ws;                  // 8192*768
    unsigned short* wtp = xb + (size_t)8192 * E_;                 // 3*768*768
    unsigned short* qkb = wtp + (size_t)3 * E_ * E_;              // 2*8192*768 (Q,K)
    unsigned short* vtg = qkb + (size_t)2 * 8192 * E_;            // 2*12*64*4096 (V^T)

    hipLaunchKernelGGL(cvt_fused, dim3(3776), dim3(256), 0, stream,
                       hs, xb, 8192 * E_ / 4, Wq, Wk, Wv, wtp);
    hipLaunchKernelGGL(qkv_gemm, dim3(1152), dim3(256), 0, stream, xb, wtp, bq, bk, bv, qkb, vtg);
    hipLaunchKernelGGL(attn, dim3(768), dim3(256), 0, stream, qkb, vtg, am, out);
}